// Round 1
// baseline (2352.775 us; speedup 1.0000x reference)
//
#include <hip/hip_runtime.h>
#include <hip/hip_bf16.h>
#include <math.h>

#define NUSER 100000
#define NITEM 100000
#define NEDGE 600000
#define HID   128
#define OUTD  64

// ---------------------------------------------------------------------------
// Stage 1: h = [x_user; x_item] @ W_proj + b_proj     (fp32, vector ALU)
// Block: 256 threads, 32 rows x 128 cols per block. W_proj (64KB) in LDS.
// Thread (tr=tid/32, tc=tid%32) computes rows tr*4+i, cols tc+32*j (4x4).
// ---------------------------------------------------------------------------
__global__ __launch_bounds__(256) void proj_kernel(
    const float* __restrict__ xu, const float* __restrict__ xi,
    const float* __restrict__ W, const float* __restrict__ b,
    float* __restrict__ h)
{
    __shared__ float Wl[128 * 128];   // 64 KB
    __shared__ float Xl[32 * 128];    // 16 KB
    const int tid = threadIdx.x;
    const int r0  = blockIdx.x * 32;

    // Load W_proj (4096 float4 / 256 threads = 16 each), coalesced.
    for (int i = tid; i < 128 * 128 / 4; i += 256)
        ((float4*)Wl)[i] = ((const float4*)W)[i];

    // Load 32 rows of x (user rows < NUSER, else item rows).
    for (int i = tid; i < 32 * 128 / 4; i += 256) {
        int row = i >> 5, c4 = i & 31;
        int gr = r0 + row;
        const float4* src = (gr < NUSER)
            ? (const float4*)(xu + (size_t)gr * 128)
            : (const float4*)(xi + (size_t)(gr - NUSER) * 128);
        ((float4*)Xl)[i] = src[c4];
    }
    __syncthreads();

    const int tc = tid & 31;
    const int tr = tid >> 5;

    float acc[4][4];
    #pragma unroll
    for (int j = 0; j < 4; j++) {
        float bv = b[tc + 32 * j];
        #pragma unroll
        for (int i = 0; i < 4; i++) acc[i][j] = bv;
    }

    // k-loop unrolled by 4 so Xl reads become ds_read_b128.
    for (int k0 = 0; k0 < 128; k0 += 4) {
        float4 xv[4];
        #pragma unroll
        for (int i = 0; i < 4; i++)
            xv[i] = *(const float4*)&Xl[(tr * 4 + i) * 128 + k0];
        #pragma unroll
        for (int kk = 0; kk < 4; kk++) {
            float wv[4];
            #pragma unroll
            for (int j = 0; j < 4; j++)
                wv[j] = Wl[(k0 + kk) * 128 + tc + 32 * j];
            #pragma unroll
            for (int i = 0; i < 4; i++) {
                float xvk = (&xv[i].x)[kk];
                #pragma unroll
                for (int j = 0; j < 4; j++)
                    acc[i][j] = fmaf(xvk, wv[j], acc[i][j]);
            }
        }
    }

    float* hb = h + (size_t)r0 * 128;
    #pragma unroll
    for (int i = 0; i < 4; i++)
        #pragma unroll
        for (int j = 0; j < 4; j++)
            hb[(tr * 4 + i) * 128 + tc + 32 * j] = acc[i][j];
}

// ---------------------------------------------------------------------------
// Stage 2: degree histograms (as float so stage 3 needs no conversion)
// ---------------------------------------------------------------------------
__global__ void zero_f32(float* __restrict__ p, int n) {
    int i = blockIdx.x * blockDim.x + threadIdx.x;
    if (i < n) p[i] = 0.f;
}

__global__ void count_deg(const int* __restrict__ e1d, const int* __restrict__ e2d,
                          float* __restrict__ deg1, float* __restrict__ deg2) {
    int i = blockIdx.x * blockDim.x + threadIdx.x;
    if (i < NEDGE)            atomicAdd(&deg1[e1d[i]], 1.0f);
    else if (i < 2 * NEDGE)   atomicAdd(&deg2[e2d[i - NEDGE]], 1.0f);
}

// ---------------------------------------------------------------------------
// Stage 3: acc[d] = (ar1*deg1[d] + ar2*deg2[d]) * h_user[d]   (full overwrite)
// ---------------------------------------------------------------------------
__global__ __launch_bounds__(256) void init_acc(
    const float* __restrict__ h, const float* __restrict__ deg1,
    const float* __restrict__ deg2, const float* __restrict__ ar1p,
    const float* __restrict__ ar2p, float* __restrict__ acc)
{
    int i = blockIdx.x * blockDim.x + threadIdx.x;   // over NUSER*32 float4s
    if (i >= NUSER * 32) return;
    int node = i >> 5;
    float s = ar1p[0] * deg1[node] + ar2p[0] * deg2[node];
    float4 v = ((const float4*)h)[i];
    float4 r;
    r.x = v.x * s; r.y = v.y * s; r.z = v.z * s; r.w = v.w * s;
    ((float4*)acc)[i] = r;
}

// ---------------------------------------------------------------------------
// Stage 4: per-edge scatter of al * h[src] into acc[dst].
// 32 threads per edge, each thread: one float4 gather + 4 fp32 atomics.
// ---------------------------------------------------------------------------
__global__ __launch_bounds__(256) void scatter(
    const float* __restrict__ h,
    const int* __restrict__ e1s, const int* __restrict__ e1d,
    const int* __restrict__ e2s, const int* __restrict__ e2d,
    const float* __restrict__ al1p, const float* __restrict__ al2p,
    float* __restrict__ acc)
{
    long long idx = (long long)blockIdx.x * blockDim.x + threadIdx.x;
    int e  = (int)(idx >> 5);
    int c4 = (int)(idx & 31);
    if (e >= 2 * NEDGE) return;

    const float* hrow; int dst; float a;
    if (e < NEDGE) {
        hrow = h + (size_t)e1s[e] * 128;
        dst  = e1d[e];
        a    = al1p[0];
    } else {
        int e2 = e - NEDGE;
        hrow = h + (size_t)(NUSER + e2s[e2]) * 128;
        dst  = e2d[e2];
        a    = al2p[0];
    }
    float4 v = ((const float4*)hrow)[c4];
    float* d = acc + (size_t)dst * 128 + c4 * 4;
    atomicAdd(d + 0, v.x * a);
    atomicAdd(d + 1, v.y * a);
    atomicAdd(d + 2, v.z * a);
    atomicAdd(d + 3, v.w * a);
}

// ---------------------------------------------------------------------------
// Stage 5: out_user = elu(acc) @ W_out + b_out.  4 nodes / 256-thread block.
// ---------------------------------------------------------------------------
__global__ __launch_bounds__(256) void finalize(
    const float* __restrict__ acc, const float* __restrict__ Wo,
    const float* __restrict__ bo, float* __restrict__ out)
{
    __shared__ float Wl[128 * 64];   // 32 KB
    __shared__ float Al[4 * 128];
    const int tid = threadIdx.x;
    const int n0  = blockIdx.x * 4;

    for (int i = tid; i < 128 * 64 / 4; i += 256)
        ((float4*)Wl)[i] = ((const float4*)Wo)[i];

    for (int i = tid; i < 512; i += 256) {
        int n = i >> 7, k = i & 127;
        float v = acc[(size_t)(n0 + n) * 128 + k];
        Al[i] = v > 0.f ? v : expm1f(v);
    }
    __syncthreads();

    const int n = tid >> 6;     // 0..3
    const int t = tid & 63;     // output column
    float s = bo[t];
    const float* a = Al + (n << 7);
    #pragma unroll 8
    for (int k = 0; k < 128; k++)
        s = fmaf(a[k], Wl[k * 64 + t], s);
    out[(size_t)(n0 + n) * 64 + t] = s;
}

// ---------------------------------------------------------------------------
// Stage 6: out_item = 0 (also re-zeros acc region for the item output)
// ---------------------------------------------------------------------------
__global__ void zero4(float4* __restrict__ p, int n4) {
    int i = blockIdx.x * blockDim.x + threadIdx.x;
    if (i < n4) p[i] = make_float4(0.f, 0.f, 0.f, 0.f);
}

extern "C" void kernel_launch(void* const* d_in, const int* in_sizes, int n_in,
                              void* d_out, int out_size, void* d_ws, size_t ws_size,
                              hipStream_t stream) {
    const float* xu  = (const float*)d_in[0];
    const float* xi  = (const float*)d_in[1];
    const float* Wp  = (const float*)d_in[2];
    const float* bp  = (const float*)d_in[3];
    const float* Wo  = (const float*)d_in[4];
    const float* bo  = (const float*)d_in[5];
    const float* al1 = (const float*)d_in[6];
    const float* ar1 = (const float*)d_in[7];
    const float* al2 = (const float*)d_in[8];
    const float* ar2 = (const float*)d_in[9];
    const int* e1s = (const int*)d_in[10];
    const int* e1d = (const int*)d_in[11];
    const int* e2s = (const int*)d_in[12];
    const int* e2d = (const int*)d_in[13];

    float* out = (float*)d_out;
    // out_item region (NUSER*128 floats) doubles as the fp32 accumulator.
    float* acc = out + (size_t)NUSER * OUTD;

    // Workspace layout: h[(NU+NI)*128] | deg1[NU] | deg2[NU]  (~103.2 MB)
    float* h    = (float*)d_ws;
    float* deg1 = h + (size_t)(NUSER + NITEM) * HID;
    float* deg2 = deg1 + NUSER;

    // 1: shared projection for both node types
    proj_kernel<<<(NUSER + NITEM) / 32, 256, 0, stream>>>(xu, xi, Wp, bp, h);

    // 2: degree histograms
    zero_f32<<<(2 * NUSER + 255) / 256, 256, 0, stream>>>(deg1, 2 * NUSER);
    count_deg<<<(2 * NEDGE + 255) / 256, 256, 0, stream>>>(e1d, e2d, deg1, deg2);

    // 3: acc = (ar1*deg1 + ar2*deg2) * h_user   (the two 'ar' segment-sums)
    init_acc<<<(NUSER * 32 + 255) / 256, 256, 0, stream>>>(h, deg1, deg2, ar1, ar2, acc);

    // 4: acc += al * h[src] over both relations
    scatter<<<(2 * NEDGE * 32) / 256, 256, 0, stream>>>(h, e1s, e1d, e2s, e2d, al1, al2, acc);

    // 5: out_user = elu(acc) @ W_out + b_out
    finalize<<<NUSER / 4, 256, 0, stream>>>(acc, Wo, bo, out);

    // 6: out_item = elu(0) = 0
    zero4<<<(NUSER * HID / 4 + 255) / 256, 256, 0, stream>>>((float4*)acc, NUSER * HID / 4);
}

// Round 2
// 466.758 us; speedup vs baseline: 5.0407x; 5.0407x over previous
//
#include <hip/hip_runtime.h>
#include <hip/hip_bf16.h>
#include <math.h>

#define NUSER 100000
#define NITEM 100000
#define NEDGE 600000
#define HID   128
#define OUTD  64

// ---------------------------------------------------------------------------
// Stage 1: h = [x_user; x_item] @ W_proj + b_proj     (fp32, vector ALU)
// ---------------------------------------------------------------------------
__global__ __launch_bounds__(256) void proj_kernel(
    const float* __restrict__ xu, const float* __restrict__ xi,
    const float* __restrict__ W, const float* __restrict__ b,
    float* __restrict__ h)
{
    __shared__ float Wl[128 * 128];   // 64 KB
    __shared__ float Xl[32 * 128];    // 16 KB
    const int tid = threadIdx.x;
    const int r0  = blockIdx.x * 32;

    for (int i = tid; i < 128 * 128 / 4; i += 256)
        ((float4*)Wl)[i] = ((const float4*)W)[i];

    for (int i = tid; i < 32 * 128 / 4; i += 256) {
        int row = i >> 5, c4 = i & 31;
        int gr = r0 + row;
        const float4* src = (gr < NUSER)
            ? (const float4*)(xu + (size_t)gr * 128)
            : (const float4*)(xi + (size_t)(gr - NUSER) * 128);
        ((float4*)Xl)[i] = src[c4];
    }
    __syncthreads();

    const int tc = tid & 31;
    const int tr = tid >> 5;

    float acc[4][4];
    #pragma unroll
    for (int j = 0; j < 4; j++) {
        float bv = b[tc + 32 * j];
        #pragma unroll
        for (int i = 0; i < 4; i++) acc[i][j] = bv;
    }

    for (int k0 = 0; k0 < 128; k0 += 4) {
        float4 xv[4];
        #pragma unroll
        for (int i = 0; i < 4; i++)
            xv[i] = *(const float4*)&Xl[(tr * 4 + i) * 128 + k0];
        #pragma unroll
        for (int kk = 0; kk < 4; kk++) {
            float wv[4];
            #pragma unroll
            for (int j = 0; j < 4; j++)
                wv[j] = Wl[(k0 + kk) * 128 + tc + 32 * j];
            #pragma unroll
            for (int i = 0; i < 4; i++) {
                float xvk = (&xv[i].x)[kk];
                #pragma unroll
                for (int j = 0; j < 4; j++)
                    acc[i][j] = fmaf(xvk, wv[j], acc[i][j]);
            }
        }
    }

    float* hb = h + (size_t)r0 * 128;
    #pragma unroll
    for (int i = 0; i < 4; i++)
        #pragma unroll
        for (int j = 0; j < 4; j++)
            hb[(tr * 4 + i) * 128 + tc + 32 * j] = acc[i][j];
}

// ---------------------------------------------------------------------------
// Stage 2: zero the int metadata (deg1|deg2|pos contiguous)
// ---------------------------------------------------------------------------
__global__ void zero_i32(int* __restrict__ p, int n) {
    int i = blockIdx.x * blockDim.x + threadIdx.x;
    if (i < n) p[i] = 0;
}

// ---------------------------------------------------------------------------
// Stage 3: integer degree histograms per relation
// ---------------------------------------------------------------------------
__global__ void count_deg(const int* __restrict__ e1d, const int* __restrict__ e2d,
                          int* __restrict__ deg1, int* __restrict__ deg2) {
    int i = blockIdx.x * blockDim.x + threadIdx.x;
    if (i < NEDGE)            atomicAdd(&deg1[e1d[i]], 1);
    else if (i < 2 * NEDGE)   atomicAdd(&deg2[e2d[i - NEDGE]], 1);
}

// ---------------------------------------------------------------------------
// Stage 4: exclusive scan of (deg1+deg2) -> off[0..NUSER]   (3-kernel 2-level)
// ---------------------------------------------------------------------------
#define SCAN_BLOCKS 391   // ceil(100000/256)

__global__ __launch_bounds__(256) void scanA(
    const int* __restrict__ deg1, const int* __restrict__ deg2,
    int* __restrict__ off, int* __restrict__ bsum)
{
    __shared__ int sh[256];
    int t = threadIdx.x;
    int i = blockIdx.x * 256 + t;
    int d = (i < NUSER) ? deg1[i] + deg2[i] : 0;
    sh[t] = d;
    __syncthreads();
    for (int dd = 1; dd < 256; dd <<= 1) {
        int v = (t >= dd) ? sh[t - dd] : 0;
        __syncthreads();
        sh[t] += v;
        __syncthreads();
    }
    if (i < NUSER) off[i] = (t > 0) ? sh[t - 1] : 0;   // block-local exclusive
    if (t == 255) bsum[blockIdx.x] = sh[255];
}

__global__ __launch_bounds__(512) void scanB(int* __restrict__ bsum, int* __restrict__ off) {
    __shared__ int sh[512];
    int t = threadIdx.x;
    int v = (t < SCAN_BLOCKS) ? bsum[t] : 0;
    sh[t] = v;
    __syncthreads();
    for (int dd = 1; dd < 512; dd <<= 1) {
        int x = (t >= dd) ? sh[t - dd] : 0;
        __syncthreads();
        sh[t] += x;
        __syncthreads();
    }
    if (t < SCAN_BLOCKS) bsum[t] = (t > 0) ? sh[t - 1] : 0;  // exclusive block prefix
    if (t == 511) off[NUSER] = sh[511];                       // grand total
}

__global__ __launch_bounds__(256) void scanC(int* __restrict__ off, const int* __restrict__ bsum) {
    int i = blockIdx.x * 256 + threadIdx.x;
    if (i < NUSER) off[i] += bsum[blockIdx.x];
}

// ---------------------------------------------------------------------------
// Stage 5: fill adjacency (dst-sorted src list; rel encoded by src>=NUSER)
// ---------------------------------------------------------------------------
__global__ void fill_adj(const int* __restrict__ e1s, const int* __restrict__ e1d,
                         const int* __restrict__ e2s, const int* __restrict__ e2d,
                         const int* __restrict__ off, int* __restrict__ pos,
                         int* __restrict__ adj) {
    int i = blockIdx.x * blockDim.x + threadIdx.x;
    int src, dst;
    if (i < NEDGE)          { src = e1s[i];               dst = e1d[i]; }
    else if (i < 2 * NEDGE) { src = NUSER + e2s[i - NEDGE]; dst = e2d[i - NEDGE]; }
    else return;
    int slot = off[dst] + atomicAdd(&pos[dst], 1);
    adj[slot] = src;
}

// ---------------------------------------------------------------------------
// Stage 6: gather — one wave per dst node. float2 per lane (128 cols / 64).
// acc[node] = elu( (ar1*deg1 + ar2*deg2) * h_user[node] + sum al_r * h[src] )
// ---------------------------------------------------------------------------
__global__ __launch_bounds__(256) void gather(
    const float* __restrict__ h, const int* __restrict__ adj,
    const int* __restrict__ off, const int* __restrict__ deg1,
    const int* __restrict__ deg2,
    const float* __restrict__ al1p, const float* __restrict__ ar1p,
    const float* __restrict__ al2p, const float* __restrict__ ar2p,
    float* __restrict__ acc)
{
    int wid  = (int)((blockIdx.x * 256 + threadIdx.x) >> 6);
    int lane = threadIdx.x & 63;
    if (wid >= NUSER) return;

    const float al1 = al1p[0], al2 = al2p[0];
    const float sc  = ar1p[0] * (float)deg1[wid] + ar2p[0] * (float)deg2[wid];

    float2 hv = ((const float2*)(h + (size_t)wid * 128))[lane];
    float sx = sc * hv.x, sy = sc * hv.y;

    int e  = off[wid];
    int e1 = off[wid + 1];
    for (; e + 2 <= e1; e += 2) {
        int s0 = adj[e], s1 = adj[e + 1];
        float a0 = (s0 < NUSER) ? al1 : al2;
        float a1 = (s1 < NUSER) ? al1 : al2;
        float2 v0 = ((const float2*)(h + (size_t)s0 * 128))[lane];
        float2 v1 = ((const float2*)(h + (size_t)s1 * 128))[lane];
        sx = fmaf(a0, v0.x, sx); sy = fmaf(a0, v0.y, sy);
        sx = fmaf(a1, v1.x, sx); sy = fmaf(a1, v1.y, sy);
    }
    if (e < e1) {
        int s0 = adj[e];
        float a0 = (s0 < NUSER) ? al1 : al2;
        float2 v0 = ((const float2*)(h + (size_t)s0 * 128))[lane];
        sx = fmaf(a0, v0.x, sx); sy = fmaf(a0, v0.y, sy);
    }

    sx = sx > 0.f ? sx : expm1f(sx);
    sy = sy > 0.f ? sy : expm1f(sy);
    ((float2*)(acc + (size_t)wid * 128))[lane] = make_float2(sx, sy);
}

// ---------------------------------------------------------------------------
// Stage 7: out_user = acc(elu'd) @ W_out + b_out.  4 nodes / 256-thread block.
// ---------------------------------------------------------------------------
__global__ __launch_bounds__(256) void finalize(
    const float* __restrict__ acc, const float* __restrict__ Wo,
    const float* __restrict__ bo, float* __restrict__ out)
{
    __shared__ float Wl[128 * 64];   // 32 KB
    __shared__ float Al[4 * 128];
    const int tid = threadIdx.x;
    const int n0  = blockIdx.x * 4;

    for (int i = tid; i < 128 * 64 / 4; i += 256)
        ((float4*)Wl)[i] = ((const float4*)Wo)[i];

    for (int i = tid; i < 512; i += 256)
        Al[i] = acc[(size_t)n0 * 128 + i];
    __syncthreads();

    const int n = tid >> 6;
    const int t = tid & 63;
    float s = bo[t];
    const float* a = Al + (n << 7);
    #pragma unroll 8
    for (int k = 0; k < 128; k++)
        s = fmaf(a[k], Wl[k * 64 + t], s);
    out[(size_t)(n0 + n) * 64 + t] = s;
}

// ---------------------------------------------------------------------------
// Stage 8: out_item = elu(0) = 0
// ---------------------------------------------------------------------------
__global__ void zero4(float4* __restrict__ p, int n4) {
    int i = blockIdx.x * blockDim.x + threadIdx.x;
    if (i < n4) p[i] = make_float4(0.f, 0.f, 0.f, 0.f);
}

extern "C" void kernel_launch(void* const* d_in, const int* in_sizes, int n_in,
                              void* d_out, int out_size, void* d_ws, size_t ws_size,
                              hipStream_t stream) {
    const float* xu  = (const float*)d_in[0];
    const float* xi  = (const float*)d_in[1];
    const float* Wp  = (const float*)d_in[2];
    const float* bp  = (const float*)d_in[3];
    const float* Wo  = (const float*)d_in[4];
    const float* bo  = (const float*)d_in[5];
    const float* al1 = (const float*)d_in[6];
    const float* ar1 = (const float*)d_in[7];
    const float* al2 = (const float*)d_in[8];
    const float* ar2 = (const float*)d_in[9];
    const int* e1s = (const int*)d_in[10];
    const int* e1d = (const int*)d_in[11];
    const int* e2s = (const int*)d_in[12];
    const int* e2d = (const int*)d_in[13];

    float* out = (float*)d_out;
    float* acc = out + (size_t)NUSER * OUTD;   // out_item region = elu buffer

    // h in workspace (102.4 MB)
    float* h = (float*)d_ws;

    // Int metadata lives in the out_user region (free until finalize):
    // deg1[NU] | deg2[NU] | pos[NU] | off[NU+1] | bsum[512] | adj[2E]
    int* meta = (int*)out;
    int* deg1 = meta;
    int* deg2 = meta + NUSER;
    int* pos  = meta + 2 * NUSER;
    int* off  = meta + 3 * NUSER;            // NUSER+1 entries
    int* bsum = meta + 4 * NUSER + 64;       // 512 entries
    int* adj  = meta + 4 * NUSER + 1024;     // 2E = 1.2M entries (total 6.4MB < 25.6MB)

    // 1: shared projection for both node types
    proj_kernel<<<(NUSER + NITEM) / 32, 256, 0, stream>>>(xu, xi, Wp, bp, h);

    // 2: zero deg1|deg2|pos (contiguous 3*NUSER ints)
    zero_i32<<<(3 * NUSER + 255) / 256, 256, 0, stream>>>(deg1, 3 * NUSER);

    // 3: degree histograms (int atomics)
    count_deg<<<(2 * NEDGE + 255) / 256, 256, 0, stream>>>(e1d, e2d, deg1, deg2);

    // 4: exclusive scan -> off
    scanA<<<SCAN_BLOCKS, 256, 0, stream>>>(deg1, deg2, off, bsum);
    scanB<<<1, 512, 0, stream>>>(bsum, off);
    scanC<<<SCAN_BLOCKS, 256, 0, stream>>>(off, bsum);

    // 5: dst-sorted adjacency
    fill_adj<<<(2 * NEDGE + 255) / 256, 256, 0, stream>>>(e1s, e1d, e2s, e2d, off, pos, adj);

    // 6: atomic-free gather + ELU (one wave per user node)
    gather<<<(NUSER * 64) / 256, 256, 0, stream>>>(h, adj, off, deg1, deg2,
                                                   al1, ar1, al2, ar2, acc);

    // 7: out_user = acc @ W_out + b_out   (overwrites metadata region)
    finalize<<<NUSER / 4, 256, 0, stream>>>(acc, Wo, bo, out);

    // 8: out_item = 0
    zero4<<<(NUSER * HID / 4 + 255) / 256, 256, 0, stream>>>((float4*)acc, NUSER * HID / 4);
}

// Round 3
// 386.433 us; speedup vs baseline: 6.0884x; 1.2079x over previous
//
#include <hip/hip_runtime.h>
#include <hip/hip_bf16.h>
#include <math.h>

#define NUSER 100000
#define NITEM 100000
#define NEDGE 600000
#define HID   128
#define OUTD  64
#define LDA   136   // padded LDS stride in bf16 elems (136*2=272B, 16B-aligned, conflict-free)

typedef __attribute__((ext_vector_type(8))) short  bf16x8;
typedef __attribute__((ext_vector_type(4))) float  f32x4;
typedef __attribute__((ext_vector_type(4))) unsigned short u16x4;

__device__ inline unsigned short f2bf(float f) {
    __hip_bfloat16 h = __float2bfloat16(f);
    return *reinterpret_cast<unsigned short*>(&h);
}

// ---------------------------------------------------------------------------
// Stage 0: W_proj fp32 [k][col] -> bf16 transposed wt[col][k]
// ---------------------------------------------------------------------------
__global__ void prep_w(const float* __restrict__ W, unsigned short* __restrict__ wt) {
    int i = blockIdx.x * 256 + threadIdx.x;
    if (i >= 128 * 128) return;
    int k = i >> 7, c = i & 127;
    wt[c * 128 + k] = f2bf(W[i]);
}

// ---------------------------------------------------------------------------
// Stage 1: h = [x_user; x_item] @ W_proj + b_proj  via bf16 MFMA, fp32 out.
// Block: 256 thr (4 waves), 64 rows x 128 cols. Wave w -> cols [w*32,w*32+32).
// ---------------------------------------------------------------------------
__global__ __launch_bounds__(256) void proj_mfma(
    const float* __restrict__ xu, const float* __restrict__ xi,
    const unsigned short* __restrict__ wt, const float* __restrict__ b,
    float* __restrict__ h)
{
    __shared__ unsigned short Wl[128 * LDA];  // 34.8 KB
    __shared__ unsigned short Al[64 * LDA];   // 17.4 KB
    const int tid = threadIdx.x;
    const int r0  = blockIdx.x * 64;

    // stage W (bf16, already [col][k]): 2048 16B chunks
    for (int i = tid; i < 2048; i += 256) {
        int col = i >> 4, kc = i & 15;
        *(bf16x8*)&Wl[col * LDA + kc * 8] = *(const bf16x8*)&wt[col * 128 + kc * 8];
    }
    // stage A: fp32 -> bf16 convert, [row][k]
    for (int i = tid; i < 2048; i += 256) {
        int row = i >> 5, c4 = i & 31;
        int gr = r0 + row;
        const float4* src = (gr < NUSER)
            ? (const float4*)(xu + (size_t)gr * 128)
            : (const float4*)(xi + (size_t)(gr - NUSER) * 128);
        float4 v = src[c4];
        u16x4 p;
        p.x = f2bf(v.x); p.y = f2bf(v.y); p.z = f2bf(v.z); p.w = f2bf(v.w);
        *(u16x4*)&Al[row * LDA + c4 * 4] = p;
    }
    __syncthreads();

    const int w    = tid >> 6;
    const int lane = tid & 63;
    const int lrow = lane & 15;
    const int lk   = (lane >> 4) * 8;

    f32x4 acc[4][2] = {};

    #pragma unroll
    for (int kc = 0; kc < 4; kc++) {
        const int ko = kc * 32 + lk;
        bf16x8 b0 = *(const bf16x8*)&Wl[(w * 32 + lrow) * LDA + ko];
        bf16x8 b1 = *(const bf16x8*)&Wl[(w * 32 + 16 + lrow) * LDA + ko];
        #pragma unroll
        for (int rt = 0; rt < 4; rt++) {
            bf16x8 aa = *(const bf16x8*)&Al[(rt * 16 + lrow) * LDA + ko];
            acc[rt][0] = __builtin_amdgcn_mfma_f32_16x16x32_bf16(aa, b0, acc[rt][0], 0, 0, 0);
            acc[rt][1] = __builtin_amdgcn_mfma_f32_16x16x32_bf16(aa, b1, acc[rt][1], 0, 0, 0);
        }
    }

    const float bv0 = b[w * 32 + lrow];
    const float bv1 = b[w * 32 + 16 + lrow];
    #pragma unroll
    for (int rt = 0; rt < 4; rt++) {
        #pragma unroll
        for (int ct = 0; ct < 2; ct++) {
            int col = w * 32 + ct * 16 + lrow;
            float bv = ct ? bv1 : bv0;
            #pragma unroll
            for (int r = 0; r < 4; r++) {
                int row = r0 + rt * 16 + (lane >> 4) * 4 + r;
                h[(size_t)row * 128 + col] = acc[rt][ct][r] + bv;
            }
        }
    }
}

// ---------------------------------------------------------------------------
// Stage 2: zero the int metadata (deg1|deg2|pos contiguous)
// ---------------------------------------------------------------------------
__global__ void zero_i32(int* __restrict__ p, int n) {
    int i = blockIdx.x * blockDim.x + threadIdx.x;
    if (i < n) p[i] = 0;
}

// ---------------------------------------------------------------------------
// Stage 3: integer degree histograms per relation
// ---------------------------------------------------------------------------
__global__ void count_deg(const int* __restrict__ e1d, const int* __restrict__ e2d,
                          int* __restrict__ deg1, int* __restrict__ deg2) {
    int i = blockIdx.x * blockDim.x + threadIdx.x;
    if (i < NEDGE)            atomicAdd(&deg1[e1d[i]], 1);
    else if (i < 2 * NEDGE)   atomicAdd(&deg2[e2d[i - NEDGE]], 1);
}

// ---------------------------------------------------------------------------
// Stage 4: exclusive scan of (deg1+deg2) -> off[0..NUSER]
// ---------------------------------------------------------------------------
#define SCAN_BLOCKS 391   // ceil(100000/256)

__global__ __launch_bounds__(256) void scanA(
    const int* __restrict__ deg1, const int* __restrict__ deg2,
    int* __restrict__ off, int* __restrict__ bsum)
{
    __shared__ int sh[256];
    int t = threadIdx.x;
    int i = blockIdx.x * 256 + t;
    int d = (i < NUSER) ? deg1[i] + deg2[i] : 0;
    sh[t] = d;
    __syncthreads();
    for (int dd = 1; dd < 256; dd <<= 1) {
        int v = (t >= dd) ? sh[t - dd] : 0;
        __syncthreads();
        sh[t] += v;
        __syncthreads();
    }
    if (i < NUSER) off[i] = (t > 0) ? sh[t - 1] : 0;
    if (t == 255) bsum[blockIdx.x] = sh[255];
}

__global__ __launch_bounds__(512) void scanB(int* __restrict__ bsum, int* __restrict__ off) {
    __shared__ int sh[512];
    int t = threadIdx.x;
    int v = (t < SCAN_BLOCKS) ? bsum[t] : 0;
    sh[t] = v;
    __syncthreads();
    for (int dd = 1; dd < 512; dd <<= 1) {
        int x = (t >= dd) ? sh[t - dd] : 0;
        __syncthreads();
        sh[t] += x;
        __syncthreads();
    }
    if (t < SCAN_BLOCKS) bsum[t] = (t > 0) ? sh[t - 1] : 0;
    if (t == 511) off[NUSER] = sh[511];
}

__global__ __launch_bounds__(256) void scanC(int* __restrict__ off, const int* __restrict__ bsum) {
    int i = blockIdx.x * 256 + threadIdx.x;
    if (i < NUSER) off[i] += bsum[blockIdx.x];
}

// ---------------------------------------------------------------------------
// Stage 5: fill adjacency (dst-sorted src list; rel encoded by src>=NUSER)
// ---------------------------------------------------------------------------
__global__ void fill_adj(const int* __restrict__ e1s, const int* __restrict__ e1d,
                         const int* __restrict__ e2s, const int* __restrict__ e2d,
                         const int* __restrict__ off, int* __restrict__ pos,
                         int* __restrict__ adj) {
    int i = blockIdx.x * blockDim.x + threadIdx.x;
    int src, dst;
    if (i < NEDGE)          { src = e1s[i];                 dst = e1d[i]; }
    else if (i < 2 * NEDGE) { src = NUSER + e2s[i - NEDGE]; dst = e2d[i - NEDGE]; }
    else return;
    int slot = off[dst] + atomicAdd(&pos[dst], 1);
    adj[slot] = src;
}

// ---------------------------------------------------------------------------
// Stage 6: gather — one wave per dst node; float2 per lane; fused ELU.
// ---------------------------------------------------------------------------
__global__ __launch_bounds__(256) void gather(
    const float* __restrict__ h, const int* __restrict__ adj,
    const int* __restrict__ off, const int* __restrict__ deg1,
    const int* __restrict__ deg2,
    const float* __restrict__ al1p, const float* __restrict__ ar1p,
    const float* __restrict__ al2p, const float* __restrict__ ar2p,
    float* __restrict__ acc)
{
    int wid  = (int)((blockIdx.x * 256 + threadIdx.x) >> 6);
    int lane = threadIdx.x & 63;
    if (wid >= NUSER) return;

    const float al1 = al1p[0], al2 = al2p[0];
    const float sc  = ar1p[0] * (float)deg1[wid] + ar2p[0] * (float)deg2[wid];

    float2 hv = ((const float2*)(h + (size_t)wid * 128))[lane];
    float sx = sc * hv.x, sy = sc * hv.y;

    int e  = off[wid];
    int e1 = off[wid + 1];
    for (; e + 2 <= e1; e += 2) {
        int s0 = adj[e], s1 = adj[e + 1];
        float a0 = (s0 < NUSER) ? al1 : al2;
        float a1 = (s1 < NUSER) ? al1 : al2;
        float2 v0 = ((const float2*)(h + (size_t)s0 * 128))[lane];
        float2 v1 = ((const float2*)(h + (size_t)s1 * 128))[lane];
        sx = fmaf(a0, v0.x, sx); sy = fmaf(a0, v0.y, sy);
        sx = fmaf(a1, v1.x, sx); sy = fmaf(a1, v1.y, sy);
    }
    if (e < e1) {
        int s0 = adj[e];
        float a0 = (s0 < NUSER) ? al1 : al2;
        float2 v0 = ((const float2*)(h + (size_t)s0 * 128))[lane];
        sx = fmaf(a0, v0.x, sx); sy = fmaf(a0, v0.y, sy);
    }

    sx = sx > 0.f ? sx : expm1f(sx);
    sy = sy > 0.f ? sy : expm1f(sy);
    ((float2*)(acc + (size_t)wid * 128))[lane] = make_float2(sx, sy);
}

// ---------------------------------------------------------------------------
// Stage 7: out_user = acc(elu'd) @ W_out + b_out.
// ---------------------------------------------------------------------------
__global__ __launch_bounds__(256) void finalize(
    const float* __restrict__ acc, const float* __restrict__ Wo,
    const float* __restrict__ bo, float* __restrict__ out)
{
    __shared__ float Wl[128 * 64];
    __shared__ float Al[4 * 128];
    const int tid = threadIdx.x;
    const int n0  = blockIdx.x * 4;

    for (int i = tid; i < 128 * 64 / 4; i += 256)
        ((float4*)Wl)[i] = ((const float4*)Wo)[i];

    for (int i = tid; i < 512; i += 256)
        Al[i] = acc[(size_t)n0 * 128 + i];
    __syncthreads();

    const int n = tid >> 6;
    const int t = tid & 63;
    float s = bo[t];
    const float* a = Al + (n << 7);
    #pragma unroll 8
    for (int k = 0; k < 128; k++)
        s = fmaf(a[k], Wl[k * 64 + t], s);
    out[(size_t)(n0 + n) * 64 + t] = s;
}

// ---------------------------------------------------------------------------
// Stage 8: out_item = elu(0) = 0
// ---------------------------------------------------------------------------
__global__ void zero4(float4* __restrict__ p, int n4) {
    int i = blockIdx.x * blockDim.x + threadIdx.x;
    if (i < n4) p[i] = make_float4(0.f, 0.f, 0.f, 0.f);
}

extern "C" void kernel_launch(void* const* d_in, const int* in_sizes, int n_in,
                              void* d_out, int out_size, void* d_ws, size_t ws_size,
                              hipStream_t stream) {
    const float* xu  = (const float*)d_in[0];
    const float* xi  = (const float*)d_in[1];
    const float* Wp  = (const float*)d_in[2];
    const float* bp  = (const float*)d_in[3];
    const float* Wo  = (const float*)d_in[4];
    const float* bo  = (const float*)d_in[5];
    const float* al1 = (const float*)d_in[6];
    const float* ar1 = (const float*)d_in[7];
    const float* al2 = (const float*)d_in[8];
    const float* ar2 = (const float*)d_in[9];
    const int* e1s = (const int*)d_in[10];
    const int* e1d = (const int*)d_in[11];
    const int* e2s = (const int*)d_in[12];
    const int* e2d = (const int*)d_in[13];

    float* out = (float*)d_out;
    float* acc = out + (size_t)NUSER * OUTD;   // out_item region = elu buffer

    // Workspace: h[(NU+NI)*128] f32 | wt[128*128] bf16
    float* h = (float*)d_ws;
    unsigned short* wt = (unsigned short*)(h + (size_t)(NUSER + NITEM) * HID);

    // Int metadata in the out_user region (free until finalize):
    int* meta = (int*)out;
    int* deg1 = meta;
    int* deg2 = meta + NUSER;
    int* pos  = meta + 2 * NUSER;
    int* off  = meta + 3 * NUSER;
    int* bsum = meta + 4 * NUSER + 64;
    int* adj  = meta + 4 * NUSER + 1024;

    // 0: W -> bf16 transposed
    prep_w<<<64, 256, 0, stream>>>(Wp, wt);

    // 1: MFMA projection for both node types
    proj_mfma<<<(NUSER + NITEM) / 64, 256, 0, stream>>>(xu, xi, wt, bp, h);

    // 2: zero deg1|deg2|pos
    zero_i32<<<(3 * NUSER + 255) / 256, 256, 0, stream>>>(deg1, 3 * NUSER);

    // 3: degree histograms
    count_deg<<<(2 * NEDGE + 255) / 256, 256, 0, stream>>>(e1d, e2d, deg1, deg2);

    // 4: exclusive scan -> off
    scanA<<<SCAN_BLOCKS, 256, 0, stream>>>(deg1, deg2, off, bsum);
    scanB<<<1, 512, 0, stream>>>(bsum, off);
    scanC<<<SCAN_BLOCKS, 256, 0, stream>>>(off, bsum);

    // 5: dst-sorted adjacency
    fill_adj<<<(2 * NEDGE + 255) / 256, 256, 0, stream>>>(e1s, e1d, e2s, e2d, off, pos, adj);

    // 6: atomic-free gather + ELU
    gather<<<(NUSER * 64) / 256, 256, 0, stream>>>(h, adj, off, deg1, deg2,
                                                   al1, ar1, al2, ar2, acc);

    // 7: out_user = acc @ W_out + b_out
    finalize<<<NUSER / 4, 256, 0, stream>>>(acc, Wo, bo, out);

    // 8: out_item = 0
    zero4<<<(NUSER * HID / 4 + 255) / 256, 256, 0, stream>>>((float4*)acc, NUSER * HID / 4);
}

// Round 4
// 324.589 us; speedup vs baseline: 7.2485x; 1.1905x over previous
//
#include <hip/hip_runtime.h>
#include <hip/hip_bf16.h>
#include <math.h>

#define NUSER 100000
#define NITEM 100000
#define NEDGE 600000
#define HID   128
#define OUTD  64
#define LDA   136   // padded LDS stride in bf16 elems (proj kernel)
#define LDF   132   // padded LDS stride in f32 elems (finalize Al)

typedef __attribute__((ext_vector_type(8))) short  bf16x8;
typedef __attribute__((ext_vector_type(4))) float  f32x4;
typedef __attribute__((ext_vector_type(4))) unsigned short u16x4;

__device__ inline unsigned short f2bf(float f) {
    __hip_bfloat16 h = __float2bfloat16(f);
    return *reinterpret_cast<unsigned short*>(&h);
}

// ---------------------------------------------------------------------------
// Stage 0: W_proj fp32 [k][col] -> bf16 transposed wt[col][k]
// ---------------------------------------------------------------------------
__global__ void prep_w(const float* __restrict__ W, unsigned short* __restrict__ wt) {
    int i = blockIdx.x * 256 + threadIdx.x;
    if (i >= 128 * 128) return;
    int k = i >> 7, c = i & 127;
    wt[c * 128 + k] = f2bf(W[i]);
}

// ---------------------------------------------------------------------------
// Stage 1: h = [x_user; x_item] @ W_proj + b_proj  via bf16 MFMA, fp32 out.
// ---------------------------------------------------------------------------
__global__ __launch_bounds__(256) void proj_mfma(
    const float* __restrict__ xu, const float* __restrict__ xi,
    const unsigned short* __restrict__ wt, const float* __restrict__ b,
    float* __restrict__ h)
{
    __shared__ unsigned short Wl[128 * LDA];  // 34.8 KB
    __shared__ unsigned short Al[64 * LDA];   // 17.4 KB
    const int tid = threadIdx.x;
    const int r0  = blockIdx.x * 64;

    for (int i = tid; i < 2048; i += 256) {
        int col = i >> 4, kc = i & 15;
        *(bf16x8*)&Wl[col * LDA + kc * 8] = *(const bf16x8*)&wt[col * 128 + kc * 8];
    }
    for (int i = tid; i < 2048; i += 256) {
        int row = i >> 5, c4 = i & 31;
        int gr = r0 + row;
        const float4* src = (gr < NUSER)
            ? (const float4*)(xu + (size_t)gr * 128)
            : (const float4*)(xi + (size_t)(gr - NUSER) * 128);
        float4 v = src[c4];
        u16x4 p;
        p.x = f2bf(v.x); p.y = f2bf(v.y); p.z = f2bf(v.z); p.w = f2bf(v.w);
        *(u16x4*)&Al[row * LDA + c4 * 4] = p;
    }
    __syncthreads();

    const int w    = tid >> 6;
    const int lane = tid & 63;
    const int lrow = lane & 15;
    const int lk   = (lane >> 4) * 8;

    f32x4 acc[4][2] = {};

    #pragma unroll
    for (int kc = 0; kc < 4; kc++) {
        const int ko = kc * 32 + lk;
        bf16x8 b0 = *(const bf16x8*)&Wl[(w * 32 + lrow) * LDA + ko];
        bf16x8 b1 = *(const bf16x8*)&Wl[(w * 32 + 16 + lrow) * LDA + ko];
        #pragma unroll
        for (int rt = 0; rt < 4; rt++) {
            bf16x8 aa = *(const bf16x8*)&Al[(rt * 16 + lrow) * LDA + ko];
            acc[rt][0] = __builtin_amdgcn_mfma_f32_16x16x32_bf16(aa, b0, acc[rt][0], 0, 0, 0);
            acc[rt][1] = __builtin_amdgcn_mfma_f32_16x16x32_bf16(aa, b1, acc[rt][1], 0, 0, 0);
        }
    }

    const float bv0 = b[w * 32 + lrow];
    const float bv1 = b[w * 32 + 16 + lrow];
    #pragma unroll
    for (int rt = 0; rt < 4; rt++) {
        #pragma unroll
        for (int ct = 0; ct < 2; ct++) {
            int col = w * 32 + ct * 16 + lrow;
            float bv = ct ? bv1 : bv0;
            #pragma unroll
            for (int r = 0; r < 4; r++) {
                int row = r0 + rt * 16 + (lane >> 4) * 4 + r;
                h[(size_t)row * 128 + col] = acc[rt][ct][r] + bv;
            }
        }
    }
}

// ---------------------------------------------------------------------------
// Stage 2: zero the int metadata (deg1|deg2|pos contiguous)
// ---------------------------------------------------------------------------
__global__ void zero_i32(int* __restrict__ p, int n) {
    int i = blockIdx.x * blockDim.x + threadIdx.x;
    if (i < n) p[i] = 0;
}

// ---------------------------------------------------------------------------
// Stage 3: integer degree histograms per relation
// ---------------------------------------------------------------------------
__global__ void count_deg(const int* __restrict__ e1d, const int* __restrict__ e2d,
                          int* __restrict__ deg1, int* __restrict__ deg2) {
    int i = blockIdx.x * blockDim.x + threadIdx.x;
    if (i < NEDGE)            atomicAdd(&deg1[e1d[i]], 1);
    else if (i < 2 * NEDGE)   atomicAdd(&deg2[e2d[i - NEDGE]], 1);
}

// ---------------------------------------------------------------------------
// Stage 4: exclusive scan of (deg1+deg2) -> off[0..NUSER]
// ---------------------------------------------------------------------------
#define SCAN_BLOCKS 391   // ceil(100000/256)

__global__ __launch_bounds__(256) void scanA(
    const int* __restrict__ deg1, const int* __restrict__ deg2,
    int* __restrict__ off, int* __restrict__ bsum)
{
    __shared__ int sh[256];
    int t = threadIdx.x;
    int i = blockIdx.x * 256 + t;
    int d = (i < NUSER) ? deg1[i] + deg2[i] : 0;
    sh[t] = d;
    __syncthreads();
    for (int dd = 1; dd < 256; dd <<= 1) {
        int v = (t >= dd) ? sh[t - dd] : 0;
        __syncthreads();
        sh[t] += v;
        __syncthreads();
    }
    if (i < NUSER) off[i] = (t > 0) ? sh[t - 1] : 0;
    if (t == 255) bsum[blockIdx.x] = sh[255];
}

__global__ __launch_bounds__(512) void scanB(int* __restrict__ bsum, int* __restrict__ off) {
    __shared__ int sh[512];
    int t = threadIdx.x;
    int v = (t < SCAN_BLOCKS) ? bsum[t] : 0;
    sh[t] = v;
    __syncthreads();
    for (int dd = 1; dd < 512; dd <<= 1) {
        int x = (t >= dd) ? sh[t - dd] : 0;
        __syncthreads();
        sh[t] += x;
        __syncthreads();
    }
    if (t < SCAN_BLOCKS) bsum[t] = (t > 0) ? sh[t - 1] : 0;
    if (t == 511) off[NUSER] = sh[511];
}

__global__ __launch_bounds__(256) void scanC(int* __restrict__ off, const int* __restrict__ bsum) {
    int i = blockIdx.x * 256 + threadIdx.x;
    if (i < NUSER) off[i] += bsum[blockIdx.x];
}

// ---------------------------------------------------------------------------
// Stage 5: fill adjacency (dst-sorted src list; rel encoded by src>=NUSER)
// ---------------------------------------------------------------------------
__global__ void fill_adj(const int* __restrict__ e1s, const int* __restrict__ e1d,
                         const int* __restrict__ e2s, const int* __restrict__ e2d,
                         const int* __restrict__ off, int* __restrict__ pos,
                         int* __restrict__ adj) {
    int i = blockIdx.x * blockDim.x + threadIdx.x;
    int src, dst;
    if (i < NEDGE)          { src = e1s[i];                 dst = e1d[i]; }
    else if (i < 2 * NEDGE) { src = NUSER + e2s[i - NEDGE]; dst = e2d[i - NEDGE]; }
    else return;
    int slot = off[dst] + atomicAdd(&pos[dst], 1);
    adj[slot] = src;
}

// ---------------------------------------------------------------------------
// Stage 6: gather — one wave per dst node; float2 per lane; fused ELU.
// ---------------------------------------------------------------------------
__global__ __launch_bounds__(256) void gather(
    const float* __restrict__ h, const int* __restrict__ adj,
    const int* __restrict__ off, const int* __restrict__ deg1,
    const int* __restrict__ deg2,
    const float* __restrict__ al1p, const float* __restrict__ ar1p,
    const float* __restrict__ al2p, const float* __restrict__ ar2p,
    float* __restrict__ acc)
{
    int wid  = (int)((blockIdx.x * 256 + threadIdx.x) >> 6);
    int lane = threadIdx.x & 63;
    if (wid >= NUSER) return;

    const float al1 = al1p[0], al2 = al2p[0];
    const float sc  = ar1p[0] * (float)deg1[wid] + ar2p[0] * (float)deg2[wid];

    float2 hv = ((const float2*)(h + (size_t)wid * 128))[lane];
    float sx = sc * hv.x, sy = sc * hv.y;

    int e  = off[wid];
    int e1 = off[wid + 1];
    for (; e + 2 <= e1; e += 2) {
        int s0 = adj[e], s1 = adj[e + 1];
        float a0 = (s0 < NUSER) ? al1 : al2;
        float a1 = (s1 < NUSER) ? al1 : al2;
        float2 v0 = ((const float2*)(h + (size_t)s0 * 128))[lane];
        float2 v1 = ((const float2*)(h + (size_t)s1 * 128))[lane];
        sx = fmaf(a0, v0.x, sx); sy = fmaf(a0, v0.y, sy);
        sx = fmaf(a1, v1.x, sx); sy = fmaf(a1, v1.y, sy);
    }
    if (e < e1) {
        int s0 = adj[e];
        float a0 = (s0 < NUSER) ? al1 : al2;
        float2 v0 = ((const float2*)(h + (size_t)s0 * 128))[lane];
        sx = fmaf(a0, v0.x, sx); sy = fmaf(a0, v0.y, sy);
    }

    sx = sx > 0.f ? sx : expm1f(sx);
    sy = sy > 0.f ? sy : expm1f(sy);
    ((float2*)(acc + (size_t)wid * 128))[lane] = make_float2(sx, sy);
}

// ---------------------------------------------------------------------------
// Stage 7: out_user = acc(elu'd) @ W_out + b_out.  Register-tiled fp32 GEMM.
// Block: 256 thr, 64 nodes x 64 cols. Thread (tr=tid>>4, tc=tid&15) computes
// rows tr*4..+3, cols tc*4..+3. k-unroll 4 -> all LDS reads are b128.
// ---------------------------------------------------------------------------
__global__ __launch_bounds__(256) void finalize(
    const float* __restrict__ acc, const float* __restrict__ Wo,
    const float* __restrict__ bo, float* __restrict__ out)
{
    __shared__ float Wl[128 * 64];    // 32 KB, [k][col]
    __shared__ float Al[64 * LDF];    // 33.8 KB, [row][k], padded stride
    const int tid = threadIdx.x;
    const int n0  = blockIdx.x * 64;

    for (int i = tid; i < 128 * 64 / 4; i += 256)
        ((float4*)Wl)[i] = ((const float4*)Wo)[i];

    for (int i = tid; i < 2048; i += 256) {
        int row = i >> 5, c4 = i & 31;
        int gr = n0 + row;
        float4 v = (gr < NUSER) ? ((const float4*)(acc + (size_t)gr * 128))[c4]
                                : make_float4(0.f, 0.f, 0.f, 0.f);
        *(float4*)&Al[row * LDF + c4 * 4] = v;
    }
    __syncthreads();

    const int tr = tid >> 4;   // 0..15 -> rows tr*4..+3
    const int tc = tid & 15;   // 0..15 -> cols tc*4..+3

    float s[4][4];
    {
        float4 bv = *(const float4*)&bo[tc * 4];
        #pragma unroll
        for (int i = 0; i < 4; i++) {
            s[i][0] = bv.x; s[i][1] = bv.y; s[i][2] = bv.z; s[i][3] = bv.w;
        }
    }

    for (int k0 = 0; k0 < 128; k0 += 4) {
        float4 av[4];
        #pragma unroll
        for (int i = 0; i < 4; i++)
            av[i] = *(const float4*)&Al[(tr * 4 + i) * LDF + k0];
        #pragma unroll
        for (int kk = 0; kk < 4; kk++) {
            float4 wv = *(const float4*)&Wl[(k0 + kk) * 64 + tc * 4];
            #pragma unroll
            for (int i = 0; i < 4; i++) {
                float a = (&av[i].x)[kk];
                s[i][0] = fmaf(a, wv.x, s[i][0]);
                s[i][1] = fmaf(a, wv.y, s[i][1]);
                s[i][2] = fmaf(a, wv.z, s[i][2]);
                s[i][3] = fmaf(a, wv.w, s[i][3]);
            }
        }
    }

    #pragma unroll
    for (int i = 0; i < 4; i++) {
        int gr = n0 + tr * 4 + i;
        if (gr < NUSER) {
            float4 o = make_float4(s[i][0], s[i][1], s[i][2], s[i][3]);
            *(float4*)&out[(size_t)gr * 64 + tc * 4] = o;
        }
    }
}

// ---------------------------------------------------------------------------
// Stage 8: out_item = elu(0) = 0
// ---------------------------------------------------------------------------
__global__ void zero4(float4* __restrict__ p, int n4) {
    int i = blockIdx.x * blockDim.x + threadIdx.x;
    if (i < n4) p[i] = make_float4(0.f, 0.f, 0.f, 0.f);
}

extern "C" void kernel_launch(void* const* d_in, const int* in_sizes, int n_in,
                              void* d_out, int out_size, void* d_ws, size_t ws_size,
                              hipStream_t stream) {
    const float* xu  = (const float*)d_in[0];
    const float* xi  = (const float*)d_in[1];
    const float* Wp  = (const float*)d_in[2];
    const float* bp  = (const float*)d_in[3];
    const float* Wo  = (const float*)d_in[4];
    const float* bo  = (const float*)d_in[5];
    const float* al1 = (const float*)d_in[6];
    const float* ar1 = (const float*)d_in[7];
    const float* al2 = (const float*)d_in[8];
    const float* ar2 = (const float*)d_in[9];
    const int* e1s = (const int*)d_in[10];
    const int* e1d = (const int*)d_in[11];
    const int* e2s = (const int*)d_in[12];
    const int* e2d = (const int*)d_in[13];

    float* out = (float*)d_out;
    float* acc = out + (size_t)NUSER * OUTD;   // out_item region = elu buffer

    // Workspace: h[(NU+NI)*128] f32 | wt[128*128] bf16
    float* h = (float*)d_ws;
    unsigned short* wt = (unsigned short*)(h + (size_t)(NUSER + NITEM) * HID);

    // Int metadata in the out_user region (free until finalize):
    int* meta = (int*)out;
    int* deg1 = meta;
    int* deg2 = meta + NUSER;
    int* pos  = meta + 2 * NUSER;
    int* off  = meta + 3 * NUSER;
    int* bsum = meta + 4 * NUSER + 64;
    int* adj  = meta + 4 * NUSER + 1024;

    // 0: W -> bf16 transposed
    prep_w<<<64, 256, 0, stream>>>(Wp, wt);

    // 1: MFMA projection for both node types
    proj_mfma<<<(NUSER + NITEM) / 64, 256, 0, stream>>>(xu, xi, wt, bp, h);

    // 2: zero deg1|deg2|pos
    zero_i32<<<(3 * NUSER + 255) / 256, 256, 0, stream>>>(deg1, 3 * NUSER);

    // 3: degree histograms
    count_deg<<<(2 * NEDGE + 255) / 256, 256, 0, stream>>>(e1d, e2d, deg1, deg2);

    // 4: exclusive scan -> off
    scanA<<<SCAN_BLOCKS, 256, 0, stream>>>(deg1, deg2, off, bsum);
    scanB<<<1, 512, 0, stream>>>(bsum, off);
    scanC<<<SCAN_BLOCKS, 256, 0, stream>>>(off, bsum);

    // 5: dst-sorted adjacency
    fill_adj<<<(2 * NEDGE + 255) / 256, 256, 0, stream>>>(e1s, e1d, e2s, e2d, off, pos, adj);

    // 6: atomic-free gather + ELU
    gather<<<(NUSER * 64) / 256, 256, 0, stream>>>(h, adj, off, deg1, deg2,
                                                   al1, ar1, al2, ar2, acc);

    // 7: out_user = acc @ W_out + b_out   (register-tiled fp32 GEMM)
    finalize<<<(NUSER + 63) / 64, 256, 0, stream>>>(acc, Wo, bo, out);

    // 8: out_item = 0
    zero4<<<(NUSER * HID / 4 + 255) / 256, 256, 0, stream>>>((float4*)acc, NUSER * HID / 4);
}

// Round 5
// 291.700 us; speedup vs baseline: 8.0657x; 1.1127x over previous
//
#include <hip/hip_runtime.h>
#include <hip/hip_bf16.h>
#include <math.h>

#define NUSER 100000
#define NITEM 100000
#define NEDGE 600000
#define HID   128
#define OUTD  64
#define LDA   136   // padded LDS stride in bf16 elems (proj kernel)
#define LDF   132   // padded LDS stride in f32 elems (finalize Al)

typedef __attribute__((ext_vector_type(8))) short  bf16x8;
typedef __attribute__((ext_vector_type(4))) float  f32x4;
typedef __attribute__((ext_vector_type(4))) unsigned short u16x4;

__device__ inline unsigned short f2bf(float f) {
    __hip_bfloat16 h = __float2bfloat16(f);
    return *reinterpret_cast<unsigned short*>(&h);
}

// unpack one uint holding two bf16 (lo = col 2j, hi = col 2j+1)
__device__ inline void bf2x(unsigned int u, float& lo, float& hi) {
    union { unsigned int i; float f; } a, b;
    a.i = u << 16;
    b.i = u & 0xffff0000u;
    lo = a.f; hi = b.f;
}

// ---------------------------------------------------------------------------
// Stage 0: W_proj fp32 [k][col] -> bf16 transposed wt[col][k]
// ---------------------------------------------------------------------------
__global__ void prep_w(const float* __restrict__ W, unsigned short* __restrict__ wt) {
    int i = blockIdx.x * 256 + threadIdx.x;
    if (i >= 128 * 128) return;
    int k = i >> 7, c = i & 127;
    wt[c * 128 + k] = f2bf(W[i]);
}

// ---------------------------------------------------------------------------
// Stage 1: h = [x_user; x_item] @ W_proj + b_proj  via bf16 MFMA.
// h stored as bf16 (halves gather traffic; unique h = 51 MB -> L3-resident).
// ---------------------------------------------------------------------------
__global__ __launch_bounds__(256) void proj_mfma(
    const float* __restrict__ xu, const float* __restrict__ xi,
    const unsigned short* __restrict__ wt, const float* __restrict__ b,
    unsigned short* __restrict__ h)
{
    __shared__ unsigned short Wl[128 * LDA];  // 34.8 KB
    __shared__ unsigned short Al[64 * LDA];   // 17.4 KB
    const int tid = threadIdx.x;
    const int r0  = blockIdx.x * 64;

    for (int i = tid; i < 2048; i += 256) {
        int col = i >> 4, kc = i & 15;
        *(bf16x8*)&Wl[col * LDA + kc * 8] = *(const bf16x8*)&wt[col * 128 + kc * 8];
    }
    for (int i = tid; i < 2048; i += 256) {
        int row = i >> 5, c4 = i & 31;
        int gr = r0 + row;
        const float4* src = (gr < NUSER)
            ? (const float4*)(xu + (size_t)gr * 128)
            : (const float4*)(xi + (size_t)(gr - NUSER) * 128);
        float4 v = src[c4];
        u16x4 p;
        p.x = f2bf(v.x); p.y = f2bf(v.y); p.z = f2bf(v.z); p.w = f2bf(v.w);
        *(u16x4*)&Al[row * LDA + c4 * 4] = p;
    }
    __syncthreads();

    const int w    = tid >> 6;
    const int lane = tid & 63;
    const int lrow = lane & 15;
    const int lk   = (lane >> 4) * 8;

    f32x4 acc[4][2] = {};

    #pragma unroll
    for (int kc = 0; kc < 4; kc++) {
        const int ko = kc * 32 + lk;
        bf16x8 b0 = *(const bf16x8*)&Wl[(w * 32 + lrow) * LDA + ko];
        bf16x8 b1 = *(const bf16x8*)&Wl[(w * 32 + 16 + lrow) * LDA + ko];
        #pragma unroll
        for (int rt = 0; rt < 4; rt++) {
            bf16x8 aa = *(const bf16x8*)&Al[(rt * 16 + lrow) * LDA + ko];
            acc[rt][0] = __builtin_amdgcn_mfma_f32_16x16x32_bf16(aa, b0, acc[rt][0], 0, 0, 0);
            acc[rt][1] = __builtin_amdgcn_mfma_f32_16x16x32_bf16(aa, b1, acc[rt][1], 0, 0, 0);
        }
    }

    const float bv0 = b[w * 32 + lrow];
    const float bv1 = b[w * 32 + 16 + lrow];
    #pragma unroll
    for (int rt = 0; rt < 4; rt++) {
        #pragma unroll
        for (int ct = 0; ct < 2; ct++) {
            int col = w * 32 + ct * 16 + lrow;
            float bv = ct ? bv1 : bv0;
            #pragma unroll
            for (int r = 0; r < 4; r++) {
                int row = r0 + rt * 16 + (lane >> 4) * 4 + r;
                h[(size_t)row * 128 + col] = f2bf(acc[rt][ct][r] + bv);
            }
        }
    }
}

// ---------------------------------------------------------------------------
// Stage 2: zero the int metadata (deg1|deg2|pos contiguous)
// ---------------------------------------------------------------------------
__global__ void zero_i32(int* __restrict__ p, int n) {
    int i = blockIdx.x * blockDim.x + threadIdx.x;
    if (i < n) p[i] = 0;
}

// ---------------------------------------------------------------------------
// Stage 3: integer degree histograms per relation
// ---------------------------------------------------------------------------
__global__ void count_deg(const int* __restrict__ e1d, const int* __restrict__ e2d,
                          int* __restrict__ deg1, int* __restrict__ deg2) {
    int i = blockIdx.x * blockDim.x + threadIdx.x;
    if (i < NEDGE)            atomicAdd(&deg1[e1d[i]], 1);
    else if (i < 2 * NEDGE)   atomicAdd(&deg2[e2d[i - NEDGE]], 1);
}

// ---------------------------------------------------------------------------
// Stage 4: exclusive scan of (deg1+deg2) -> off[0..NUSER]
// ---------------------------------------------------------------------------
#define SCAN_BLOCKS 391   // ceil(100000/256)

__global__ __launch_bounds__(256) void scanA(
    const int* __restrict__ deg1, const int* __restrict__ deg2,
    int* __restrict__ off, int* __restrict__ bsum)
{
    __shared__ int sh[256];
    int t = threadIdx.x;
    int i = blockIdx.x * 256 + t;
    int d = (i < NUSER) ? deg1[i] + deg2[i] : 0;
    sh[t] = d;
    __syncthreads();
    for (int dd = 1; dd < 256; dd <<= 1) {
        int v = (t >= dd) ? sh[t - dd] : 0;
        __syncthreads();
        sh[t] += v;
        __syncthreads();
    }
    if (i < NUSER) off[i] = (t > 0) ? sh[t - 1] : 0;
    if (t == 255) bsum[blockIdx.x] = sh[255];
}

__global__ __launch_bounds__(512) void scanB(int* __restrict__ bsum, int* __restrict__ off) {
    __shared__ int sh[512];
    int t = threadIdx.x;
    int v = (t < SCAN_BLOCKS) ? bsum[t] : 0;
    sh[t] = v;
    __syncthreads();
    for (int dd = 1; dd < 512; dd <<= 1) {
        int x = (t >= dd) ? sh[t - dd] : 0;
        __syncthreads();
        sh[t] += x;
        __syncthreads();
    }
    if (t < SCAN_BLOCKS) bsum[t] = (t > 0) ? sh[t - 1] : 0;
    if (t == 511) off[NUSER] = sh[511];
}

__global__ __launch_bounds__(256) void scanC(int* __restrict__ off, const int* __restrict__ bsum) {
    int i = blockIdx.x * 256 + threadIdx.x;
    if (i < NUSER) off[i] += bsum[blockIdx.x];
}

// ---------------------------------------------------------------------------
// Stage 5: fill adjacency (dst-sorted src list; rel encoded by src>=NUSER)
// ---------------------------------------------------------------------------
__global__ void fill_adj(const int* __restrict__ e1s, const int* __restrict__ e1d,
                         const int* __restrict__ e2s, const int* __restrict__ e2d,
                         const int* __restrict__ off, int* __restrict__ pos,
                         int* __restrict__ adj) {
    int i = blockIdx.x * blockDim.x + threadIdx.x;
    int src, dst;
    if (i < NEDGE)          { src = e1s[i];                 dst = e1d[i]; }
    else if (i < 2 * NEDGE) { src = NUSER + e2s[i - NEDGE]; dst = e2d[i - NEDGE]; }
    else return;
    int slot = off[dst] + atomicAdd(&pos[dst], 1);
    adj[slot] = src;
}

// ---------------------------------------------------------------------------
// Stage 6: gather — one wave per dst node; one dword (2 bf16 cols) per lane.
// acc[node] = elu( (ar1*deg1 + ar2*deg2) * h_user[node] + sum al_r * h[src] )
// ---------------------------------------------------------------------------
__global__ __launch_bounds__(256) void gather(
    const unsigned short* __restrict__ h, const int* __restrict__ adj,
    const int* __restrict__ off, const int* __restrict__ deg1,
    const int* __restrict__ deg2,
    const float* __restrict__ al1p, const float* __restrict__ ar1p,
    const float* __restrict__ al2p, const float* __restrict__ ar2p,
    float* __restrict__ acc)
{
    int wid  = (int)((blockIdx.x * 256 + threadIdx.x) >> 6);
    int lane = threadIdx.x & 63;
    if (wid >= NUSER) return;

    const unsigned int* h32 = (const unsigned int*)h;  // row = 64 dwords

    const float al1 = al1p[0], al2 = al2p[0];
    const float sc  = ar1p[0] * (float)deg1[wid] + ar2p[0] * (float)deg2[wid];

    float lo, hi;
    bf2x(h32[(size_t)wid * 64 + lane], lo, hi);
    float sx = sc * lo, sy = sc * hi;

    int e    = off[wid];
    int eend = off[wid + 1];
    for (; e + 4 <= eend; e += 4) {
        int s0 = adj[e], s1 = adj[e + 1], s2 = adj[e + 2], s3 = adj[e + 3];
        unsigned int u0 = h32[(size_t)s0 * 64 + lane];
        unsigned int u1 = h32[(size_t)s1 * 64 + lane];
        unsigned int u2 = h32[(size_t)s2 * 64 + lane];
        unsigned int u3 = h32[(size_t)s3 * 64 + lane];
        float a0 = (s0 < NUSER) ? al1 : al2;
        float a1 = (s1 < NUSER) ? al1 : al2;
        float a2 = (s2 < NUSER) ? al1 : al2;
        float a3 = (s3 < NUSER) ? al1 : al2;
        float x0, y0, x1, y1, x2, y2, x3, y3;
        bf2x(u0, x0, y0); bf2x(u1, x1, y1); bf2x(u2, x2, y2); bf2x(u3, x3, y3);
        sx = fmaf(a0, x0, sx); sy = fmaf(a0, y0, sy);
        sx = fmaf(a1, x1, sx); sy = fmaf(a1, y1, sy);
        sx = fmaf(a2, x2, sx); sy = fmaf(a2, y2, sy);
        sx = fmaf(a3, x3, sx); sy = fmaf(a3, y3, sy);
    }
    for (; e < eend; e++) {
        int s0 = adj[e];
        float a0 = (s0 < NUSER) ? al1 : al2;
        float x0, y0;
        bf2x(h32[(size_t)s0 * 64 + lane], x0, y0);
        sx = fmaf(a0, x0, sx); sy = fmaf(a0, y0, sy);
    }

    sx = sx > 0.f ? sx : expm1f(sx);
    sy = sy > 0.f ? sy : expm1f(sy);
    ((float2*)(acc + (size_t)wid * 128))[lane] = make_float2(sx, sy);
}

// ---------------------------------------------------------------------------
// Stage 7: out_user = acc(elu'd) @ W_out + b_out.  Register-tiled fp32 GEMM.
// ---------------------------------------------------------------------------
__global__ __launch_bounds__(256) void finalize(
    const float* __restrict__ acc, const float* __restrict__ Wo,
    const float* __restrict__ bo, float* __restrict__ out)
{
    __shared__ float Wl[128 * 64];    // 32 KB, [k][col]
    __shared__ float Al[64 * LDF];    // 33.8 KB, [row][k]
    const int tid = threadIdx.x;
    const int n0  = blockIdx.x * 64;

    for (int i = tid; i < 128 * 64 / 4; i += 256)
        ((float4*)Wl)[i] = ((const float4*)Wo)[i];

    for (int i = tid; i < 2048; i += 256) {
        int row = i >> 5, c4 = i & 31;
        int gr = n0 + row;
        float4 v = (gr < NUSER) ? ((const float4*)(acc + (size_t)gr * 128))[c4]
                                : make_float4(0.f, 0.f, 0.f, 0.f);
        *(float4*)&Al[row * LDF + c4 * 4] = v;
    }
    __syncthreads();

    const int tr = tid >> 4;
    const int tc = tid & 15;

    float s[4][4];
    {
        float4 bv = *(const float4*)&bo[tc * 4];
        #pragma unroll
        for (int i = 0; i < 4; i++) {
            s[i][0] = bv.x; s[i][1] = bv.y; s[i][2] = bv.z; s[i][3] = bv.w;
        }
    }

    for (int k0 = 0; k0 < 128; k0 += 4) {
        float4 av[4];
        #pragma unroll
        for (int i = 0; i < 4; i++)
            av[i] = *(const float4*)&Al[(tr * 4 + i) * LDF + k0];
        #pragma unroll
        for (int kk = 0; kk < 4; kk++) {
            float4 wv = *(const float4*)&Wl[(k0 + kk) * 64 + tc * 4];
            #pragma unroll
            for (int i = 0; i < 4; i++) {
                float a = (&av[i].x)[kk];
                s[i][0] = fmaf(a, wv.x, s[i][0]);
                s[i][1] = fmaf(a, wv.y, s[i][1]);
                s[i][2] = fmaf(a, wv.z, s[i][2]);
                s[i][3] = fmaf(a, wv.w, s[i][3]);
            }
        }
    }

    #pragma unroll
    for (int i = 0; i < 4; i++) {
        int gr = n0 + tr * 4 + i;
        if (gr < NUSER) {
            float4 o = make_float4(s[i][0], s[i][1], s[i][2], s[i][3]);
            *(float4*)&out[(size_t)gr * 64 + tc * 4] = o;
        }
    }
}

// ---------------------------------------------------------------------------
// Stage 8: out_item = elu(0) = 0
// ---------------------------------------------------------------------------
__global__ void zero4(float4* __restrict__ p, int n4) {
    int i = blockIdx.x * blockDim.x + threadIdx.x;
    if (i < n4) p[i] = make_float4(0.f, 0.f, 0.f, 0.f);
}

extern "C" void kernel_launch(void* const* d_in, const int* in_sizes, int n_in,
                              void* d_out, int out_size, void* d_ws, size_t ws_size,
                              hipStream_t stream) {
    const float* xu  = (const float*)d_in[0];
    const float* xi  = (const float*)d_in[1];
    const float* Wp  = (const float*)d_in[2];
    const float* bp  = (const float*)d_in[3];
    const float* Wo  = (const float*)d_in[4];
    const float* bo  = (const float*)d_in[5];
    const float* al1 = (const float*)d_in[6];
    const float* ar1 = (const float*)d_in[7];
    const float* al2 = (const float*)d_in[8];
    const float* ar2 = (const float*)d_in[9];
    const int* e1s = (const int*)d_in[10];
    const int* e1d = (const int*)d_in[11];
    const int* e2s = (const int*)d_in[12];
    const int* e2d = (const int*)d_in[13];

    float* out = (float*)d_out;
    float* acc = out + (size_t)NUSER * OUTD;   // out_item region = elu buffer

    // Workspace: h[(NU+NI)*128] bf16 (51.2 MB) | wt[128*128] bf16
    unsigned short* h  = (unsigned short*)d_ws;
    unsigned short* wt = h + (size_t)(NUSER + NITEM) * HID;

    // Int metadata in the out_user region (free until finalize):
    int* meta = (int*)out;
    int* deg1 = meta;
    int* deg2 = meta + NUSER;
    int* pos  = meta + 2 * NUSER;
    int* off  = meta + 3 * NUSER;
    int* bsum = meta + 4 * NUSER + 64;
    int* adj  = meta + 4 * NUSER + 1024;

    // 0: W -> bf16 transposed
    prep_w<<<64, 256, 0, stream>>>(Wp, wt);

    // 1: MFMA projection for both node types (bf16 h out)
    proj_mfma<<<(NUSER + NITEM) / 64, 256, 0, stream>>>(xu, xi, wt, bp, h);

    // 2: zero deg1|deg2|pos
    zero_i32<<<(3 * NUSER + 255) / 256, 256, 0, stream>>>(deg1, 3 * NUSER);

    // 3: degree histograms
    count_deg<<<(2 * NEDGE + 255) / 256, 256, 0, stream>>>(e1d, e2d, deg1, deg2);

    // 4: exclusive scan -> off
    scanA<<<SCAN_BLOCKS, 256, 0, stream>>>(deg1, deg2, off, bsum);
    scanB<<<1, 512, 0, stream>>>(bsum, off);
    scanC<<<SCAN_BLOCKS, 256, 0, stream>>>(off, bsum);

    // 5: dst-sorted adjacency
    fill_adj<<<(2 * NEDGE + 255) / 256, 256, 0, stream>>>(e1s, e1d, e2s, e2d, off, pos, adj);

    // 6: atomic-free gather + ELU (bf16 h reads, fp32 accumulate)
    gather<<<(NUSER * 64) / 256, 256, 0, stream>>>(h, adj, off, deg1, deg2,
                                                   al1, ar1, al2, ar2, acc);

    // 7: out_user = acc @ W_out + b_out
    finalize<<<(NUSER + 63) / 64, 256, 0, stream>>>(acc, Wo, bo, out);

    // 8: out_item = 0
    zero4<<<(NUSER * HID / 4 + 255) / 256, 256, 0, stream>>>((float4*)acc, NUSER * HID / 4);
}

// Round 6
// 213.772 us; speedup vs baseline: 11.0060x; 1.3645x over previous
//
#include <hip/hip_runtime.h>
#include <hip/hip_bf16.h>
#include <math.h>

#define NUSER 100000
#define NITEM 100000
#define NEDGE 600000
#define HID   128
#define OUTD  64
#define LDA   136   // padded LDS stride in bf16 elems (proj kernel)
#define LDF   132   // padded LDS stride in f32 elems (finalize Al)
#define PROJ_BLOCKS ((NUSER + NITEM) / 64)          // 3125
#define EPB   ((2 * NEDGE + PROJ_BLOCKS - 1) / PROJ_BLOCKS)   // 384 edges/block

typedef __attribute__((ext_vector_type(8))) short  bf16x8;
typedef __attribute__((ext_vector_type(4))) float  f32x4;
typedef __attribute__((ext_vector_type(4))) unsigned short u16x4;

__device__ inline unsigned short f2bf(float f) {
    __hip_bfloat16 h = __float2bfloat16(f);
    return *reinterpret_cast<unsigned short*>(&h);
}

__device__ inline void bf2x(unsigned int u, float& lo, float& hi) {
    union { unsigned int i; float f; } a, b;
    a.i = u << 16;
    b.i = u & 0xffff0000u;
    lo = a.f; hi = b.f;
}

// ---------------------------------------------------------------------------
// Stage 0 (fused): zero deg1|deg2  +  W_proj -> bf16 transposed wt[col][k]
// ---------------------------------------------------------------------------
__global__ void prep(const float* __restrict__ W, unsigned short* __restrict__ wt,
                     int* __restrict__ deg) {
    int i = blockIdx.x * 256 + threadIdx.x;
    if (i < 2 * NUSER) deg[i] = 0;
    if (i < 128 * 128) {
        int k = i >> 7, c = i & 127;
        wt[c * 128 + k] = f2bf(W[i]);
    }
}

// ---------------------------------------------------------------------------
// Stage 1: degree histograms; the returned old count is the edge's rank
// within its (dst, relation) bucket -> no second atomic pass needed.
// ---------------------------------------------------------------------------
__global__ void count_rank(const int* __restrict__ e1d, const int* __restrict__ e2d,
                           int* __restrict__ deg1, int* __restrict__ deg2,
                           int* __restrict__ rank) {
    int i = blockIdx.x * blockDim.x + threadIdx.x;
    if (i < NEDGE)            rank[i] = atomicAdd(&deg1[e1d[i]], 1);
    else if (i < 2 * NEDGE)   rank[i] = atomicAdd(&deg2[e2d[i - NEDGE]], 1);
}

// ---------------------------------------------------------------------------
// Stage 2: exclusive scan of (deg1+deg2) -> off[0..NUSER]
// ---------------------------------------------------------------------------
#define SCAN_BLOCKS 391   // ceil(100000/256)

__global__ __launch_bounds__(256) void scanA(
    const int* __restrict__ deg1, const int* __restrict__ deg2,
    int* __restrict__ off, int* __restrict__ bsum)
{
    __shared__ int sh[256];
    int t = threadIdx.x;
    int i = blockIdx.x * 256 + t;
    int d = (i < NUSER) ? deg1[i] + deg2[i] : 0;
    sh[t] = d;
    __syncthreads();
    for (int dd = 1; dd < 256; dd <<= 1) {
        int v = (t >= dd) ? sh[t - dd] : 0;
        __syncthreads();
        sh[t] += v;
        __syncthreads();
    }
    if (i < NUSER) off[i] = (t > 0) ? sh[t - 1] : 0;
    if (t == 255) bsum[blockIdx.x] = sh[255];
}

__global__ __launch_bounds__(512) void scanB(int* __restrict__ bsum, int* __restrict__ off) {
    __shared__ int sh[512];
    int t = threadIdx.x;
    int v = (t < SCAN_BLOCKS) ? bsum[t] : 0;
    sh[t] = v;
    __syncthreads();
    for (int dd = 1; dd < 512; dd <<= 1) {
        int x = (t >= dd) ? sh[t - dd] : 0;
        __syncthreads();
        sh[t] += x;
        __syncthreads();
    }
    if (t < SCAN_BLOCKS) bsum[t] = (t > 0) ? sh[t - 1] : 0;
    if (t == 511) off[NUSER] = sh[511];
}

__global__ __launch_bounds__(256) void scanC(int* __restrict__ off, const int* __restrict__ bsum) {
    int i = blockIdx.x * 256 + threadIdx.x;
    if (i < NUSER) off[i] += bsum[blockIdx.x];
}

// ---------------------------------------------------------------------------
// Stage 3 (fused): bf16-MFMA projection  +  adjacency-fill tail.
// The scatter-write fill (latency-bound, ~0 VALU) hides under other blocks'
// MFMA work on the same CUs. Layout per dst: [rel1 edges | rel2 edges].
// ---------------------------------------------------------------------------
__global__ __launch_bounds__(256) void proj_fill(
    const float* __restrict__ xu, const float* __restrict__ xi,
    const unsigned short* __restrict__ wt, const float* __restrict__ b,
    unsigned short* __restrict__ h,
    const int* __restrict__ e1s, const int* __restrict__ e1d,
    const int* __restrict__ e2s, const int* __restrict__ e2d,
    const int* __restrict__ off, const int* __restrict__ deg1,
    const int* __restrict__ rank, int* __restrict__ adj)
{
    __shared__ unsigned short Wl[128 * LDA];  // 34.8 KB
    __shared__ unsigned short Al[64 * LDA];   // 17.4 KB
    const int tid = threadIdx.x;
    const int r0  = blockIdx.x * 64;

    for (int i = tid; i < 2048; i += 256) {
        int col = i >> 4, kc = i & 15;
        *(bf16x8*)&Wl[col * LDA + kc * 8] = *(const bf16x8*)&wt[col * 128 + kc * 8];
    }
    for (int i = tid; i < 2048; i += 256) {
        int row = i >> 5, c4 = i & 31;
        int gr = r0 + row;
        const float4* src = (gr < NUSER)
            ? (const float4*)(xu + (size_t)gr * 128)
            : (const float4*)(xi + (size_t)(gr - NUSER) * 128);
        float4 v = src[c4];
        u16x4 p;
        p.x = f2bf(v.x); p.y = f2bf(v.y); p.z = f2bf(v.z); p.w = f2bf(v.w);
        *(u16x4*)&Al[row * LDA + c4 * 4] = p;
    }
    __syncthreads();

    const int w    = tid >> 6;
    const int lane = tid & 63;
    const int lrow = lane & 15;
    const int lk   = (lane >> 4) * 8;

    f32x4 acc[4][2] = {};

    #pragma unroll
    for (int kc = 0; kc < 4; kc++) {
        const int ko = kc * 32 + lk;
        bf16x8 b0 = *(const bf16x8*)&Wl[(w * 32 + lrow) * LDA + ko];
        bf16x8 b1 = *(const bf16x8*)&Wl[(w * 32 + 16 + lrow) * LDA + ko];
        #pragma unroll
        for (int rt = 0; rt < 4; rt++) {
            bf16x8 aa = *(const bf16x8*)&Al[(rt * 16 + lrow) * LDA + ko];
            acc[rt][0] = __builtin_amdgcn_mfma_f32_16x16x32_bf16(aa, b0, acc[rt][0], 0, 0, 0);
            acc[rt][1] = __builtin_amdgcn_mfma_f32_16x16x32_bf16(aa, b1, acc[rt][1], 0, 0, 0);
        }
    }

    const float bv0 = b[w * 32 + lrow];
    const float bv1 = b[w * 32 + 16 + lrow];
    #pragma unroll
    for (int rt = 0; rt < 4; rt++) {
        #pragma unroll
        for (int ct = 0; ct < 2; ct++) {
            int col = w * 32 + ct * 16 + lrow;
            float bv = ct ? bv1 : bv0;
            #pragma unroll
            for (int r = 0; r < 4; r++) {
                int row = r0 + rt * 16 + (lane >> 4) * 4 + r;
                h[(size_t)row * 128 + col] = f2bf(acc[rt][ct][r] + bv);
            }
        }
    }

    // ---- adjacency-fill tail: this block's 384-edge chunk (no atomics) ----
    const int base = blockIdx.x * EPB;
    const int lim  = (base + EPB < 2 * NEDGE) ? base + EPB : 2 * NEDGE;
    for (int i = base + tid; i < lim; i += 256) {
        int src, dst, slot;
        if (i < NEDGE) {
            src  = e1s[i];
            dst  = e1d[i];
            slot = off[dst] + rank[i];
        } else {
            int j = i - NEDGE;
            src  = NUSER + e2s[j];
            dst  = e2d[j];
            slot = off[dst] + deg1[dst] + rank[i];
        }
        adj[slot] = src;
    }
}

// ---------------------------------------------------------------------------
// Stage 4: gather — one wave per dst node; one dword (2 bf16 cols) per lane.
// ---------------------------------------------------------------------------
__global__ __launch_bounds__(256) void gather(
    const unsigned short* __restrict__ h, const int* __restrict__ adj,
    const int* __restrict__ off, const int* __restrict__ deg1,
    const int* __restrict__ deg2,
    const float* __restrict__ al1p, const float* __restrict__ ar1p,
    const float* __restrict__ al2p, const float* __restrict__ ar2p,
    float* __restrict__ acc)
{
    int wid  = (int)((blockIdx.x * 256 + threadIdx.x) >> 6);
    int lane = threadIdx.x & 63;
    if (wid >= NUSER) return;

    const unsigned int* h32 = (const unsigned int*)h;

    const float al1 = al1p[0], al2 = al2p[0];
    const float sc  = ar1p[0] * (float)deg1[wid] + ar2p[0] * (float)deg2[wid];

    float lo, hi;
    bf2x(h32[(size_t)wid * 64 + lane], lo, hi);
    float sx = sc * lo, sy = sc * hi;

    int e    = off[wid];
    int eend = off[wid + 1];
    for (; e + 4 <= eend; e += 4) {
        int s0 = adj[e], s1 = adj[e + 1], s2 = adj[e + 2], s3 = adj[e + 3];
        unsigned int u0 = h32[(size_t)s0 * 64 + lane];
        unsigned int u1 = h32[(size_t)s1 * 64 + lane];
        unsigned int u2 = h32[(size_t)s2 * 64 + lane];
        unsigned int u3 = h32[(size_t)s3 * 64 + lane];
        float a0 = (s0 < NUSER) ? al1 : al2;
        float a1 = (s1 < NUSER) ? al1 : al2;
        float a2 = (s2 < NUSER) ? al1 : al2;
        float a3 = (s3 < NUSER) ? al1 : al2;
        float x0, y0, x1, y1, x2, y2, x3, y3;
        bf2x(u0, x0, y0); bf2x(u1, x1, y1); bf2x(u2, x2, y2); bf2x(u3, x3, y3);
        sx = fmaf(a0, x0, sx); sy = fmaf(a0, y0, sy);
        sx = fmaf(a1, x1, sx); sy = fmaf(a1, y1, sy);
        sx = fmaf(a2, x2, sx); sy = fmaf(a2, y2, sy);
        sx = fmaf(a3, x3, sx); sy = fmaf(a3, y3, sy);
    }
    for (; e < eend; e++) {
        int s0 = adj[e];
        float a0 = (s0 < NUSER) ? al1 : al2;
        float x0, y0;
        bf2x(h32[(size_t)s0 * 64 + lane], x0, y0);
        sx = fmaf(a0, x0, sx); sy = fmaf(a0, y0, sy);
    }

    sx = sx > 0.f ? sx : expm1f(sx);
    sy = sy > 0.f ? sy : expm1f(sy);
    ((float2*)(acc + (size_t)wid * 128))[lane] = make_float2(sx, sy);
}

// ---------------------------------------------------------------------------
// Stage 5: out_user = acc @ W_out + b_out; then zero this block's acc slice
// (acc region == out_item, which must be elu(0) = 0).
// ---------------------------------------------------------------------------
__global__ __launch_bounds__(256) void finalize(
    const float* __restrict__ acc, const float* __restrict__ Wo,
    const float* __restrict__ bo, float* __restrict__ out,
    float* __restrict__ accw)
{
    __shared__ float Wl[128 * 64];    // 32 KB
    __shared__ float Al[64 * LDF];    // 33.8 KB
    const int tid = threadIdx.x;
    const int n0  = blockIdx.x * 64;

    for (int i = tid; i < 128 * 64 / 4; i += 256)
        ((float4*)Wl)[i] = ((const float4*)Wo)[i];

    for (int i = tid; i < 2048; i += 256) {
        int row = i >> 5, c4 = i & 31;
        int gr = n0 + row;
        float4 v = (gr < NUSER) ? ((const float4*)(acc + (size_t)gr * 128))[c4]
                                : make_float4(0.f, 0.f, 0.f, 0.f);
        *(float4*)&Al[row * LDF + c4 * 4] = v;
    }
    __syncthreads();

    // zero out_item slice now that it's staged in LDS
    for (int i = tid; i < 2048; i += 256) {
        int row = i >> 5, c4 = i & 31;
        int gr = n0 + row;
        if (gr < NUSER)
            ((float4*)(accw + (size_t)gr * 128))[c4] = make_float4(0.f, 0.f, 0.f, 0.f);
    }

    const int tr = tid >> 4;
    const int tc = tid & 15;

    float s[4][4];
    {
        float4 bv = *(const float4*)&bo[tc * 4];
        #pragma unroll
        for (int i = 0; i < 4; i++) {
            s[i][0] = bv.x; s[i][1] = bv.y; s[i][2] = bv.z; s[i][3] = bv.w;
        }
    }

    for (int k0 = 0; k0 < 128; k0 += 4) {
        float4 av[4];
        #pragma unroll
        for (int i = 0; i < 4; i++)
            av[i] = *(const float4*)&Al[(tr * 4 + i) * LDF + k0];
        #pragma unroll
        for (int kk = 0; kk < 4; kk++) {
            float4 wv = *(const float4*)&Wl[(k0 + kk) * 64 + tc * 4];
            #pragma unroll
            for (int i = 0; i < 4; i++) {
                float a = (&av[i].x)[kk];
                s[i][0] = fmaf(a, wv.x, s[i][0]);
                s[i][1] = fmaf(a, wv.y, s[i][1]);
                s[i][2] = fmaf(a, wv.z, s[i][2]);
                s[i][3] = fmaf(a, wv.w, s[i][3]);
            }
        }
    }

    #pragma unroll
    for (int i = 0; i < 4; i++) {
        int gr = n0 + tr * 4 + i;
        if (gr < NUSER) {
            float4 o = make_float4(s[i][0], s[i][1], s[i][2], s[i][3]);
            *(float4*)&out[(size_t)gr * 64 + tc * 4] = o;
        }
    }
}

extern "C" void kernel_launch(void* const* d_in, const int* in_sizes, int n_in,
                              void* d_out, int out_size, void* d_ws, size_t ws_size,
                              hipStream_t stream) {
    const float* xu  = (const float*)d_in[0];
    const float* xi  = (const float*)d_in[1];
    const float* Wp  = (const float*)d_in[2];
    const float* bp  = (const float*)d_in[3];
    const float* Wo  = (const float*)d_in[4];
    const float* bo  = (const float*)d_in[5];
    const float* al1 = (const float*)d_in[6];
    const float* ar1 = (const float*)d_in[7];
    const float* al2 = (const float*)d_in[8];
    const float* ar2 = (const float*)d_in[9];
    const int* e1s = (const int*)d_in[10];
    const int* e1d = (const int*)d_in[11];
    const int* e2s = (const int*)d_in[12];
    const int* e2d = (const int*)d_in[13];

    float* out = (float*)d_out;
    float* acc = out + (size_t)NUSER * OUTD;   // out_item region = elu buffer

    // Workspace: h[(NU+NI)*128] bf16 (51.2 MB) | wt[128*128] bf16
    unsigned short* h  = (unsigned short*)d_ws;
    unsigned short* wt = h + (size_t)(NUSER + NITEM) * HID;

    // Int metadata in the out_user region (free until finalize):
    // deg1[NU] | deg2[NU] | off[NU+1] | bsum[512] | adj[2E] | rank[2E]
    int* meta = (int*)out;
    int* deg1 = meta;
    int* deg2 = meta + NUSER;
    int* off  = meta + 2 * NUSER;
    int* bsum = meta + 3 * NUSER + 64;
    int* adj  = meta + 3 * NUSER + 1024;
    int* rank = adj + 2 * NEDGE;             // total ~10.6 MB < 25.6 MB

    // 0: zero degs + W -> bf16 transposed
    prep<<<(2 * NUSER + 255) / 256, 256, 0, stream>>>(Wp, wt, deg1);

    // 1: degree histograms, capturing per-edge rank from the atomic return
    count_rank<<<(2 * NEDGE + 255) / 256, 256, 0, stream>>>(e1d, e2d, deg1, deg2, rank);

    // 2: exclusive scan -> off
    scanA<<<SCAN_BLOCKS, 256, 0, stream>>>(deg1, deg2, off, bsum);
    scanB<<<1, 512, 0, stream>>>(bsum, off);
    scanC<<<SCAN_BLOCKS, 256, 0, stream>>>(off, bsum);

    // 3: MFMA projection + adjacency fill (fused; scatter hides under MFMA)
    proj_fill<<<PROJ_BLOCKS, 256, 0, stream>>>(xu, xi, wt, bp, h,
                                               e1s, e1d, e2s, e2d,
                                               off, deg1, rank, adj);

    // 4: atomic-free gather + ELU
    gather<<<(NUSER * 64) / 256, 256, 0, stream>>>(h, adj, off, deg1, deg2,
                                                   al1, ar1, al2, ar2, acc);

    // 5: out_user GEMM + zero out_item
    finalize<<<(NUSER + 63) / 64, 256, 0, stream>>>(acc, Wo, bo, out, acc);
}